// Round 1
// baseline (450.534 us; speedup 1.0000x reference)
//
#include <hip/hip_runtime.h>
#include <math.h>

#define BB 256
#define NN 65536

// Map float -> uint32 such that uint order == descending... (monotonic increasing map)
__device__ __forceinline__ unsigned int f2sort(float f) {
    unsigned int b = __float_as_uint(f);
    return (b & 0x80000000u) ? ~b : (b | 0x80000000u);
}

// Kernel A: compute gumbel + log-dirichlet weights, replicate reference f32
// rounding (f64 log rounded to f32 == correctly-rounded f32 log), store
// sortable uint into the mask region of d_out.
__global__ void MaskedDiffusion_weights_kernel(const float* __restrict__ U,
                                               const float* __restrict__ D,
                                               unsigned int* __restrict__ out) {
    int e = (blockIdx.x * blockDim.x + threadIdx.x) * 4;
    float4 u4 = *(const float4*)(U + e);
    float4 d4 = *(const float4*)(D + e);
    float us[4] = {u4.x, u4.y, u4.z, u4.w};
    float ds[4] = {d4.x, d4.y, d4.z, d4.w};
    unsigned int o[4];
#pragma unroll
    for (int j = 0; j < 4; j++) {
        float t1 = us[j] + 1e-7f;                    // f32 add (IEEE, matches ref)
        float t2 = (float)log((double)t1);           // ~correctly-rounded f32 log
        float t3 = (-t2) + 1e-7f;                    // f32 add
        float G  = -(float)log((double)t3);
        float lgD = (float)log((double)ds[j]);
        float w = G + lgD;                           // f32 add
        o[j] = f2sort(w);
    }
    *(uint4*)(out + e) = make_uint4(o[0], o[1], o[2], o[3]);
}

// Kernel B: one block per row. 4-pass radix select for the k-th largest
// sortable-uint, then in-place rewrite of staged uints as float mask.
__global__ __launch_bounds__(1024)
void MaskedDiffusion_select_kernel(const float* __restrict__ T,
                                   unsigned int* __restrict__ W,
                                   float* __restrict__ wout) {
    const int row = blockIdx.x;
    const int tid = threadIdx.x;
    unsigned int* ub = W + (size_t)row * NN;

    __shared__ unsigned int hist[256];
    __shared__ int s_k;
    __shared__ unsigned int s_sel, s_kneed, s_eq;
    __shared__ int s_tielist[1024];
    __shared__ int s_tiecnt;
    __shared__ int s_tieidx;

    if (tid == 0) {
        float t = T[row];
        const float pf = (float)M_PI;
        // r = 1 - cos(pi*t/2), all intermediates in f32 like the reference
        float a  = pf * t;
        float bb = a * 0.5f;
        float c  = (float)cos((double)bb);
        float r  = 1.0f - c;
        float kf = 65536.0f * r;          // exact (×2^16)
        s_k = (int)kf;                    // truncation == astype(int32)
        // w = 0.5*pi*sin(pi*(t*(1-2e-3)+1e-3)/2)  (2% tolerance — easy)
        float a1   = t * 0.998f;
        float tadj = a1 + 0.001f;
        float arg  = (pf * tadj) * 0.5f;
        float s    = (float)sin((double)arg);
        wout[row] = (float)(0.5 * M_PI) * s;
    }
    __syncthreads();

    const int k = s_k;
    if (k <= 0) {
        for (int j = 0; j < 64; j++) ((float*)ub)[j * 1024 + tid] = 0.0f;
        return;
    }
    if (k >= NN) {
        for (int j = 0; j < 64; j++) ((float*)ub)[j * 1024 + tid] = 1.0f;
        return;
    }

    unsigned int prefix = 0;
    unsigned int kneed = (unsigned int)k;
    unsigned int eqcnt = 0;

#pragma unroll
    for (int p = 0; p < 4; p++) {
        const int shift = 24 - 8 * p;
        for (int i = tid; i < 256; i += 1024) hist[i] = 0;
        __syncthreads();
        for (int j = 0; j < 64; j++) {
            unsigned int u = ub[j * 1024 + tid];
            bool match = (p == 0) || ((u >> (shift + 8)) == prefix);
            if (match) atomicAdd(&hist[(u >> shift) & 255u], 1u);
        }
        __syncthreads();
        if (tid == 0) {
            unsigned int cum = 0, kn = kneed, eq = 0;
            int sel = 0;
            for (int b2 = 255; b2 >= 0; b2--) {
                unsigned int c = hist[b2];
                if (cum + c >= kneed) { sel = b2; kn = kneed - cum; eq = c; break; }
                cum += c;
            }
            s_sel = (unsigned int)sel; s_kneed = kn; s_eq = eq;
        }
        __syncthreads();
        prefix = (prefix << 8) | s_sel;
        kneed = s_kneed;
        eqcnt = s_eq;
    }

    const unsigned int theta = prefix;
    const bool needOrder = (kneed < eqcnt);   // rare: duplicates at the cutoff
    int istar = NN;                           // default: include all equals

    if (needOrder) {
        if (tid == 0) s_tiecnt = 0;
        __syncthreads();
        for (int j = 0; j < 64; j++) {
            int idx = j * 1024 + tid;
            if (ub[idx] == theta) {
                int pos = atomicAdd(&s_tiecnt, 1);
                if (pos < 1024) s_tielist[pos] = idx;
            }
        }
        __syncthreads();
        if (tid == 0) {
            int E = s_tiecnt; if (E > 1024) E = 1024;
            // insertion sort ascending (E is tiny in practice)
            for (int a = 1; a < E; a++) {
                int v = s_tielist[a]; int b2 = a - 1;
                while (b2 >= 0 && s_tielist[b2] > v) { s_tielist[b2 + 1] = s_tielist[b2]; b2--; }
                s_tielist[b2 + 1] = v;
            }
            int kk = (int)kneed; if (kk > E) kk = E; if (kk < 1) kk = 1;
            s_tieidx = s_tielist[kk - 1];
        }
        __syncthreads();
        istar = s_tieidx;
    }

    for (int j = 0; j < 64; j++) {
        int idx = j * 1024 + tid;
        unsigned int u = ub[idx];
        bool m = (u > theta) || (u == theta && (!needOrder || idx <= istar));
        ((float*)ub)[idx] = m ? 1.0f : 0.0f;
    }
}

extern "C" void kernel_launch(void* const* d_in, const int* in_sizes, int n_in,
                              void* d_out, int out_size, void* d_ws, size_t ws_size,
                              hipStream_t stream) {
    // inputs (setup_inputs dict order): batch[B*N] i32 (unused), t[B] f32,
    // U[B*N] f32, D[B*N] f32
    const float* T = (const float*)d_in[1];
    const float* U = (const float*)d_in[2];
    const float* D = (const float*)d_in[3];
    float* out = (float*)d_out;

    unsigned int* staging = (unsigned int*)d_out;   // mask region doubles as staging
    float* wout = out + (size_t)BB * NN;

    // Kernel A: 4 elems/thread, 256 threads/block
    int blocksA = (BB * NN) / (256 * 4);
    MaskedDiffusion_weights_kernel<<<blocksA, 256, 0, stream>>>(U, D, staging);

    // Kernel B: one block per row
    MaskedDiffusion_select_kernel<<<BB, 1024, 0, stream>>>(T, staging, wout);
}

// Round 2
// 404.817 us; speedup vs baseline: 1.1129x; 1.1129x over previous
//
#include <hip/hip_runtime.h>
#include <math.h>

#define BB 256
#define NN 65536
#define NT 1024
#define EPT 64        // elements per thread (NN / NT)
#define NCHUNK 16     // float4 chunks per thread

// Monotonic map: float order == uint order (ascending)
__device__ __forceinline__ unsigned int f2sort(float f) {
    unsigned int b = __float_as_uint(f);
    return (b & 0x80000000u) ? ~b : (b | 0x80000000u);
}

__global__ __launch_bounds__(NT)
void md_fused_kernel(const float* __restrict__ Tt,
                     const float* __restrict__ U,
                     const float* __restrict__ D,
                     float* __restrict__ out,     // [B,N] mask
                     float* __restrict__ wout) {  // [B] weights
    const int row = blockIdx.x;
    const int tid = threadIdx.x;
    const float* Ur = U + (size_t)row * NN;
    const float* Dr = D + (size_t)row * NN;
    float* Or = out + (size_t)row * NN;

    __shared__ unsigned int hist[8192];      // pass1: 8192 bins; reused smaller in pass2/3
    __shared__ unsigned int chunkSum[NT];
    __shared__ unsigned int sufSum[NT];
    __shared__ int s_tielist[1024];
    __shared__ unsigned int s_sel, s_kneed, s_eq, s_theta;
    __shared__ int s_k, s_tiecnt, s_tieidx;

    if (tid == 0) {
        float t = Tt[row];
        const float pf = (float)M_PI;
        // k = int(N * (1 - cos(pi*t/2))), f32 step-for-step like reference
        float a  = pf * t;
        float bb = a * 0.5f;
        float c  = (float)cos((double)bb);
        float r  = 1.0f - c;
        s_k = (int)(65536.0f * r);
        // w = 0.5*pi*sin(pi*(t*0.998+0.001)/2)
        float tadj = t * 0.998f + 0.001f;
        float arg  = (pf * tadj) * 0.5f;
        wout[row] = (float)(0.5 * M_PI) * (float)sin((double)arg);
    }
    __syncthreads();

    const int k = s_k;
    if (k <= 0 || k >= NN) {
        const float fill = (k >= NN) ? 1.0f : 0.0f;
        float4 f4 = make_float4(fill, fill, fill, fill);
        for (int j = 0; j < NCHUNK; j++)
            *(float4*)(Or + j * 4096 + tid * 4) = f4;
        return;
    }

    // ---- compute sortable weights into registers (bit-exact vs numpy f32) ----
    unsigned int v[EPT];
#pragma unroll
    for (int j = 0; j < NCHUNK; j++) {
        int e = j * 4096 + tid * 4;
        float4 u4 = *(const float4*)(Ur + e);
        float4 d4 = *(const float4*)(Dr + e);
        float us[4] = {u4.x, u4.y, u4.z, u4.w};
        float ds[4] = {d4.x, d4.y, d4.z, d4.w};
#pragma unroll
        for (int c = 0; c < 4; c++) {
            float t1 = us[c] + 1e-7f;            // f32 add
            float t2 = (float)log((double)t1);   // correctly-rounded f32 log
            float t3 = (-t2) + 1e-7f;            // f32 add
            float G  = -(float)log((double)t3);
            float lgD = (float)log((double)ds[c]);
            v[j * 4 + c] = f2sort(G + lgD);      // f32 add then order-map
        }
    }

    // ---- pass 1: 13-bit histogram (bits 31..19), 8192 bins ----
    for (int i = tid; i < 8192; i += NT) hist[i] = 0;
    __syncthreads();
#pragma unroll
    for (int s = 0; s < EPT; s++) atomicAdd(&hist[v[s] >> 19], 1u);
    __syncthreads();

    // parallel suffix scan: thread t owns bins [t*8, t*8+8)
    {
        const int b0 = tid * 8;
        unsigned int cs = 0;
#pragma unroll
        for (int i = 0; i < 8; i++) cs += hist[b0 + i];
        chunkSum[tid] = cs;
        sufSum[tid] = cs;
        __syncthreads();
        for (int off = 1; off < NT; off <<= 1) {
            unsigned int add = (tid + off < NT) ? sufSum[tid + off] : 0u;
            __syncthreads();
            sufSum[tid] += add;
            __syncthreads();
        }
        const unsigned int kk = (unsigned int)k;
        unsigned int inc = sufSum[tid];
        unsigned int above = inc - chunkSum[tid];
        if (inc >= kk && above < kk) {          // unique thread
            unsigned int cum = above;
            for (int b = b0 + 7; b >= b0; b--) {
                unsigned int c = hist[b];
                if (cum + c >= kk) { s_sel = (unsigned int)b; s_kneed = kk - cum; s_eq = c; break; }
                cum += c;
            }
        }
        __syncthreads();
    }

    // ---- pass 2: bits 18..9 (1024 bins) among elements matching 13-bit prefix ----
    {
        hist[tid] = 0;   // exactly 1024 bins
        __syncthreads();
        const unsigned int p13 = s_sel;
#pragma unroll
        for (int s = 0; s < EPT; s++) {
            unsigned int u = v[s];
            if ((u >> 19) == p13) atomicAdd(&hist[(u >> 9) & 1023u], 1u);
        }
        __syncthreads();
        if (tid == 0) {
            unsigned int kk = s_kneed, cum = 0;
            for (int b = 1023; b >= 0; b--) {
                unsigned int c = hist[b];
                if (cum + c >= kk) { s_sel = (p13 << 10) | (unsigned int)b; s_kneed = kk - cum; s_eq = c; break; }
                cum += c;
            }
        }
        __syncthreads();
    }

    // ---- pass 3: bits 8..0 (512 bins) among elements matching 23-bit prefix ----
    {
        if (tid < 512) hist[tid] = 0;
        __syncthreads();
        const unsigned int p23 = s_sel;
#pragma unroll
        for (int s = 0; s < EPT; s++) {
            unsigned int u = v[s];
            if ((u >> 9) == p23) atomicAdd(&hist[u & 511u], 1u);
        }
        __syncthreads();
        if (tid == 0) {
            unsigned int kk = s_kneed, cum = 0;
            for (int b = 511; b >= 0; b--) {
                unsigned int c = hist[b];
                if (cum + c >= kk) { s_theta = (p23 << 9) | (unsigned int)b; s_kneed = kk - cum; s_eq = c; break; }
                cum += c;
            }
        }
        __syncthreads();
    }

    // ---- stable tie resolution (value==theta: lowest original indices win) ----
    const unsigned int theta = s_theta;
    const unsigned int kneedF = s_kneed, eqF = s_eq;
    const bool needOrder = (kneedF < eqF);
    int istar = NN;
    if (needOrder) {
        if (tid == 0) s_tiecnt = 0;
        __syncthreads();
#pragma unroll
        for (int s = 0; s < EPT; s++) {
            if (v[s] == theta) {
                int idx = (s >> 2) * 4096 + tid * 4 + (s & 3);
                int pos = atomicAdd(&s_tiecnt, 1);
                if (pos < 1024) s_tielist[pos] = idx;
            }
        }
        __syncthreads();
        if (tid == 0) {
            int E = s_tiecnt; if (E > 1024) E = 1024;
            for (int a = 1; a < E; a++) {
                int val = s_tielist[a]; int b = a - 1;
                while (b >= 0 && s_tielist[b] > val) { s_tielist[b + 1] = s_tielist[b]; b--; }
                s_tielist[b + 1] = val;
            }
            int kk = (int)kneedF; if (kk > E) kk = E; if (kk < 1) kk = 1;
            s_tieidx = s_tielist[kk - 1];
        }
        __syncthreads();
        istar = s_tieidx;
    }

    // ---- write mask straight from registers ----
#pragma unroll
    for (int j = 0; j < NCHUNK; j++) {
        int e = j * 4096 + tid * 4;
        float m[4];
#pragma unroll
        for (int c = 0; c < 4; c++) {
            unsigned int u = v[j * 4 + c];
            int idx = e + c;
            bool inc = (u > theta) || (u == theta && (!needOrder || idx <= istar));
            m[c] = inc ? 1.0f : 0.0f;
        }
        *(float4*)(Or + e) = make_float4(m[0], m[1], m[2], m[3]);
    }
}

extern "C" void kernel_launch(void* const* d_in, const int* in_sizes, int n_in,
                              void* d_out, int out_size, void* d_ws, size_t ws_size,
                              hipStream_t stream) {
    // inputs: batch[B*N] i32 (unused), t[B] f32, U[B*N] f32, D[B*N] f32
    const float* T = (const float*)d_in[1];
    const float* U = (const float*)d_in[2];
    const float* D = (const float*)d_in[3];
    float* out = (float*)d_out;
    float* wout = out + (size_t)BB * NN;

    md_fused_kernel<<<BB, NT, 0, stream>>>(T, U, D, out, wout);
}

// Round 3
// 340.318 us; speedup vs baseline: 1.3239x; 1.1895x over previous
//
#include <hip/hip_runtime.h>
#include <math.h>

#define BB 256
#define NN 65536
#define NT 1024
#define EPT 64        // elements per thread
#define NCHUNK 16     // float4 chunks per thread

// Monotonic map: float order == uint order (ascending)
__device__ __forceinline__ unsigned int f2sort(float f) {
    unsigned int b = __float_as_uint(f);
    return (b & 0x80000000u) ? ~b : (b | 0x80000000u);
}

__global__ __launch_bounds__(NT) __attribute__((amdgpu_waves_per_eu(4, 4)))
void md_fused_kernel(const float* __restrict__ Tt,
                     const float* __restrict__ U,
                     const float* __restrict__ D,
                     float* __restrict__ out,     // [B,N] mask
                     float* __restrict__ wout) {  // [B] weights
    const int row = blockIdx.x;
    const int tid = threadIdx.x;
    const int lane = tid & 63;

    const float* Ur = U + (size_t)row * NN;
    const float* Dr = D + (size_t)row * NN;
    float* Or = out + (size_t)row * NN;

    __shared__ unsigned int hist[8192];
    __shared__ unsigned int chunkSum[NT];
    __shared__ int s_tielist[1024];
    __shared__ unsigned int s_sel, s_kneed, s_eq;
    __shared__ int s_tiecnt, s_tieidx;

    // ---- per-thread k (redundant, barrier-free); f32 step-for-step like ref ----
    const float t = Tt[row];
    const float pf = (float)M_PI;
    float a  = pf * t;
    float bb = a * 0.5f;
    float c0 = (float)cos((double)bb);
    float r  = 1.0f - c0;
    const int k = (int)(65536.0f * r);
    if (tid == 0) {
        float tadj = t * 0.998f + 0.001f;
        float arg  = (pf * tadj) * 0.5f;
        wout[row] = (float)(0.5 * M_PI) * (float)sin((double)arg);
    }

    if (k <= 0 || k >= NN) {
        const float fill = (k >= NN) ? 1.0f : 0.0f;
        float4 f4 = make_float4(fill, fill, fill, fill);
        for (int j = 0; j < NCHUNK; j++)
            *(float4*)(Or + j * 4096 + tid * 4) = f4;
        return;
    }
    const unsigned int kk = (unsigned int)k;

    // ---- compute sortable weights into registers + 13-bit histogram ----
    for (int i = tid; i < 8192; i += NT) hist[i] = 0;
    __syncthreads();

    unsigned int v[EPT];
#pragma unroll
    for (int j = 0; j < NCHUNK; j++) {
        int e = j * 4096 + tid * 4;
        float4 u4 = *(const float4*)(Ur + e);
        float4 d4 = *(const float4*)(Dr + e);
        float us[4] = {u4.x, u4.y, u4.z, u4.w};
        float ds[4] = {d4.x, d4.y, d4.z, d4.w};
#pragma unroll
        for (int cc = 0; cc < 4; cc++) {
            float t1 = us[cc] + 1e-7f;            // f32 add (matches ref)
            float t2 = (float)log((double)t1);    // correctly-rounded f32 log
            float t3 = (-t2) + 1e-7f;             // f32 add
            float G  = -(float)log((double)t3);
            float lgD = (float)log((double)ds[cc]);
            unsigned int u = f2sort(G + lgD);     // f32 add, then order-map
            v[j * 4 + cc] = u;
            atomicAdd(&hist[u >> 19], 1u);
        }
    }
    __syncthreads();

    // ---- pass 1 select: all threads -> 8-bin chunk sums; wave0 suffix-scan ----
    {
        const int b0 = tid * 8;
        unsigned int cs = 0;
#pragma unroll
        for (int i = 0; i < 8; i++) cs += hist[b0 + i];
        chunkSum[tid] = cs;
    }
    __syncthreads();
    if (tid < 64) {
        const int c0i = lane * 16;
        unsigned int s = 0;
#pragma unroll
        for (int i = 0; i < 16; i++) s += chunkSum[c0i + i];
        unsigned int suf = s;
#pragma unroll
        for (int off = 1; off < 64; off <<= 1) {
            unsigned int tv = __shfl_down(suf, off);
            if (lane + off < 64) suf += tv;
        }
        unsigned int above = suf - s;
        if (suf >= kk && above < kk) {            // unique boundary lane
            unsigned int cum = above;
            for (int ci = c0i + 15; ci >= c0i; ci--) {
                unsigned int cch = chunkSum[ci];
                if (cum + cch >= kk) {
                    for (int b = ci * 8 + 7; ; b--) {
                        unsigned int c2 = hist[b];
                        if (cum + c2 >= kk) { s_sel = (unsigned int)b; s_kneed = kk - cum; s_eq = c2; break; }
                        cum += c2;
                    }
                    break;
                }
                cum += cch;
            }
        }
    }
    __syncthreads();

    // ---- pass 2: bits 18..9 (1024 bins) among 13-bit-prefix matches ----
    const unsigned int p13 = s_sel;
    const unsigned int kn1 = s_kneed;
    __syncthreads();
    hist[tid] = 0;
    __syncthreads();
#pragma unroll
    for (int s2 = 0; s2 < EPT; s2++) {
        unsigned int u = v[s2];
        if ((u >> 19) == p13) atomicAdd(&hist[(u >> 9) & 1023u], 1u);
    }
    __syncthreads();
    if (tid < 64) {
        const int c0i = lane * 16;
        unsigned int s = 0;
#pragma unroll
        for (int i = 0; i < 16; i++) s += hist[c0i + i];
        unsigned int suf = s;
#pragma unroll
        for (int off = 1; off < 64; off <<= 1) {
            unsigned int tv = __shfl_down(suf, off);
            if (lane + off < 64) suf += tv;
        }
        unsigned int above = suf - s;
        if (suf >= kn1 && above < kn1) {
            unsigned int cum = above;
            for (int b = c0i + 15; ; b--) {
                unsigned int c2 = hist[b];
                if (cum + c2 >= kn1) { s_sel = (p13 << 10) | (unsigned int)b; s_kneed = kn1 - cum; s_eq = c2; break; }
                cum += c2;
            }
        }
    }
    __syncthreads();

    // ---- pass 3: bits 8..0 (512 bins) among 23-bit-prefix matches ----
    const unsigned int p23 = s_sel;
    const unsigned int kn2 = s_kneed;
    __syncthreads();
    if (tid < 512) hist[tid] = 0;
    __syncthreads();
#pragma unroll
    for (int s2 = 0; s2 < EPT; s2++) {
        unsigned int u = v[s2];
        if ((u >> 9) == p23) atomicAdd(&hist[u & 511u], 1u);
    }
    __syncthreads();
    if (tid < 64) {
        const int c0i = lane * 8;
        unsigned int s = 0;
#pragma unroll
        for (int i = 0; i < 8; i++) s += hist[c0i + i];
        unsigned int suf = s;
#pragma unroll
        for (int off = 1; off < 64; off <<= 1) {
            unsigned int tv = __shfl_down(suf, off);
            if (lane + off < 64) suf += tv;
        }
        unsigned int above = suf - s;
        if (suf >= kn2 && above < kn2) {
            unsigned int cum = above;
            for (int b = c0i + 7; ; b--) {
                unsigned int c2 = hist[b];
                if (cum + c2 >= kn2) { s_sel = (p23 << 9) | (unsigned int)b; s_kneed = kn2 - cum; s_eq = c2; break; }
                cum += c2;
            }
        }
    }
    __syncthreads();

    // ---- stable tie resolution (value==theta: lowest original indices win) ----
    const unsigned int theta = s_sel;
    const unsigned int kneedF = s_kneed, eqF = s_eq;
    const bool needOrder = (kneedF < eqF);
    int istar = NN;
    if (needOrder) {
        if (tid == 0) s_tiecnt = 0;
        __syncthreads();
#pragma unroll
        for (int s2 = 0; s2 < EPT; s2++) {
            if (v[s2] == theta) {
                int idx = (s2 >> 2) * 4096 + tid * 4 + (s2 & 3);
                int pos = atomicAdd(&s_tiecnt, 1);
                if (pos < 1024) s_tielist[pos] = idx;
            }
        }
        __syncthreads();
        if (tid == 0) {
            int E = s_tiecnt; if (E > 1024) E = 1024;
            for (int aI = 1; aI < E; aI++) {
                int val = s_tielist[aI]; int bI = aI - 1;
                while (bI >= 0 && s_tielist[bI] > val) { s_tielist[bI + 1] = s_tielist[bI]; bI--; }
                s_tielist[bI + 1] = val;
            }
            int kk2 = (int)kneedF; if (kk2 > E) kk2 = E; if (kk2 < 1) kk2 = 1;
            s_tieidx = s_tielist[kk2 - 1];
        }
        __syncthreads();
        istar = s_tieidx;
    }

    // ---- write mask straight from registers ----
#pragma unroll
    for (int j = 0; j < NCHUNK; j++) {
        int e = j * 4096 + tid * 4;
        float m[4];
#pragma unroll
        for (int cc = 0; cc < 4; cc++) {
            unsigned int u = v[j * 4 + cc];
            int idx = e + cc;
            bool inc = (u > theta) || (u == theta && (!needOrder || idx <= istar));
            m[cc] = inc ? 1.0f : 0.0f;
        }
        *(float4*)(Or + e) = make_float4(m[0], m[1], m[2], m[3]);
    }
}

extern "C" void kernel_launch(void* const* d_in, const int* in_sizes, int n_in,
                              void* d_out, int out_size, void* d_ws, size_t ws_size,
                              hipStream_t stream) {
    // inputs: batch[B*N] i32 (unused), t[B] f32, U[B*N] f32, D[B*N] f32
    const float* T = (const float*)d_in[1];
    const float* U = (const float*)d_in[2];
    const float* D = (const float*)d_in[3];
    float* out = (float*)d_out;
    float* wout = out + (size_t)BB * NN;

    md_fused_kernel<<<BB, NT, 0, stream>>>(T, U, D, out, wout);
}

// Round 4
// 292.945 us; speedup vs baseline: 1.5379x; 1.1617x over previous
//
#include <hip/hip_runtime.h>
#include <math.h>

#define BB 256
#define NN 65536
#define NT 1024
#define NCHUNK 16     // float4 chunks per thread (16*4 = 64 elems/thread)

// Monotonic map: float order == uint order (ascending)
__device__ __forceinline__ unsigned int f2sort(float f) {
    unsigned int b = __float_as_uint(f);
    return (b & 0x80000000u) ? ~b : (b | 0x80000000u);
}

// Bit-exact vs numpy f32: each log computed in f64, rounded to f32.
__device__ __forceinline__ unsigned int wcalc(float u, float d) {
    float t1 = u + 1e-7f;                 // f32 add (matches ref)
    float t2 = (float)log((double)t1);    // correctly-rounded f32 log
    float t3 = (-t2) + 1e-7f;             // f32 add
    float G  = -(float)log((double)t3);
    float lgD = (float)log((double)d);
    return f2sort(G + lgD);               // f32 add, then order-map
}

#define CHUNKS(OP) OP(0) OP(1) OP(2) OP(3) OP(4) OP(5) OP(6) OP(7) \
                   OP(8) OP(9) OP(10) OP(11) OP(12) OP(13) OP(14) OP(15)

__global__ __launch_bounds__(NT) __attribute__((amdgpu_waves_per_eu(4, 4)))
void md_fused_kernel(const float* __restrict__ Tt,
                     const float* __restrict__ U,
                     const float* __restrict__ D,
                     float* __restrict__ out,     // [B,N] mask
                     float* __restrict__ wout) {  // [B] weights
    const int row = blockIdx.x;
    const int tid = threadIdx.x;
    const int lane = tid & 63;

    const float* Ur = U + (size_t)row * NN;
    const float* Dr = D + (size_t)row * NN;
    float* Or = out + (size_t)row * NN;

    __shared__ unsigned int hist[8192];
    __shared__ unsigned int chunkSum[NT];
    __shared__ int s_tielist[1024];
    __shared__ unsigned int s_sel, s_kneed, s_eq;
    __shared__ int s_tiecnt, s_tieidx;

    // ---- per-thread k (redundant, barrier-free); f32 step-for-step like ref ----
    const float t = Tt[row];
    const float pf = (float)M_PI;
    float aa = pf * t;
    float bb = aa * 0.5f;
    float c0 = (float)cos((double)bb);
    float r  = 1.0f - c0;
    const int k = (int)(65536.0f * r);
    if (tid == 0) {
        float tadj = t * 0.998f + 0.001f;
        float arg  = (pf * tadj) * 0.5f;
        wout[row] = (float)(0.5 * M_PI) * (float)sin((double)arg);
    }

    if (k <= 0 || k >= NN) {
        const float fill = (k >= NN) ? 1.0f : 0.0f;
        float4 f4 = make_float4(fill, fill, fill, fill);
        for (int j = 0; j < NCHUNK; j++)
            *(float4*)(Or + j * 4096 + tid * 4) = f4;
        return;
    }
    const unsigned int kk = (unsigned int)k;

    // ---- 64 sortable weights in NAMED registers (no indexable array -> no scratch) ----
    uint4 v0, v1, v2, v3, v4, v5, v6, v7, v8, v9, v10, v11, v12, v13, v14, v15;

    for (int i = tid; i < 8192; i += NT) hist[i] = 0;
    __syncthreads();

#define COMPUTE(J) { \
        int e = (J) * 4096 + tid * 4; \
        float4 u4 = *(const float4*)(Ur + e); \
        float4 d4 = *(const float4*)(Dr + e); \
        v##J.x = wcalc(u4.x, d4.x); \
        v##J.y = wcalc(u4.y, d4.y); \
        v##J.z = wcalc(u4.z, d4.z); \
        v##J.w = wcalc(u4.w, d4.w); \
        atomicAdd(&hist[v##J.x >> 19], 1u); \
        atomicAdd(&hist[v##J.y >> 19], 1u); \
        atomicAdd(&hist[v##J.z >> 19], 1u); \
        atomicAdd(&hist[v##J.w >> 19], 1u); }
    CHUNKS(COMPUTE)
#undef COMPUTE
    __syncthreads();

    // ---- pass 1 select: 8-bin chunk sums; wave0 shuffle suffix-scan ----
    {
        const int b0 = tid * 8;
        unsigned int cs = 0;
#pragma unroll
        for (int i = 0; i < 8; i++) cs += hist[b0 + i];
        chunkSum[tid] = cs;
    }
    __syncthreads();
    if (tid < 64) {
        const int c0i = lane * 16;
        unsigned int s = 0;
#pragma unroll
        for (int i = 0; i < 16; i++) s += chunkSum[c0i + i];
        unsigned int suf = s;
#pragma unroll
        for (int off = 1; off < 64; off <<= 1) {
            unsigned int tv = __shfl_down(suf, off);
            if (lane + off < 64) suf += tv;
        }
        unsigned int above = suf - s;
        if (suf >= kk && above < kk) {            // unique boundary lane
            unsigned int cum = above;
            for (int ci = c0i + 15; ci >= c0i; ci--) {
                unsigned int cch = chunkSum[ci];
                if (cum + cch >= kk) {
                    for (int b = ci * 8 + 7; ; b--) {
                        unsigned int c2 = hist[b];
                        if (cum + c2 >= kk) { s_sel = (unsigned int)b; s_kneed = kk - cum; s_eq = c2; break; }
                        cum += c2;
                    }
                    break;
                }
                cum += cch;
            }
        }
    }
    __syncthreads();

    // ---- pass 2: bits 18..9 (1024 bins) among 13-bit-prefix matches ----
    const unsigned int p13 = s_sel;
    const unsigned int kn1 = s_kneed;
    hist[tid] = 0;
    __syncthreads();
#define P2(J) { \
        if ((v##J.x >> 19) == p13) atomicAdd(&hist[(v##J.x >> 9) & 1023u], 1u); \
        if ((v##J.y >> 19) == p13) atomicAdd(&hist[(v##J.y >> 9) & 1023u], 1u); \
        if ((v##J.z >> 19) == p13) atomicAdd(&hist[(v##J.z >> 9) & 1023u], 1u); \
        if ((v##J.w >> 19) == p13) atomicAdd(&hist[(v##J.w >> 9) & 1023u], 1u); }
    CHUNKS(P2)
#undef P2
    __syncthreads();
    if (tid < 64) {
        const int c0i = lane * 16;
        unsigned int s = 0;
#pragma unroll
        for (int i = 0; i < 16; i++) s += hist[c0i + i];
        unsigned int suf = s;
#pragma unroll
        for (int off = 1; off < 64; off <<= 1) {
            unsigned int tv = __shfl_down(suf, off);
            if (lane + off < 64) suf += tv;
        }
        unsigned int above = suf - s;
        if (suf >= kn1 && above < kn1) {
            unsigned int cum = above;
            for (int b = c0i + 15; ; b--) {
                unsigned int c2 = hist[b];
                if (cum + c2 >= kn1) { s_sel = (p13 << 10) | (unsigned int)b; s_kneed = kn1 - cum; s_eq = c2; break; }
                cum += c2;
            }
        }
    }
    __syncthreads();

    // ---- pass 3: bits 8..0 (512 bins) among 23-bit-prefix matches ----
    const unsigned int p23 = s_sel;
    const unsigned int kn2 = s_kneed;
    if (tid < 512) hist[tid] = 0;
    __syncthreads();
#define P3(J) { \
        if ((v##J.x >> 9) == p23) atomicAdd(&hist[v##J.x & 511u], 1u); \
        if ((v##J.y >> 9) == p23) atomicAdd(&hist[v##J.y & 511u], 1u); \
        if ((v##J.z >> 9) == p23) atomicAdd(&hist[v##J.z & 511u], 1u); \
        if ((v##J.w >> 9) == p23) atomicAdd(&hist[v##J.w & 511u], 1u); }
    CHUNKS(P3)
#undef P3
    __syncthreads();
    if (tid < 64) {
        const int c0i = lane * 8;
        unsigned int s = 0;
#pragma unroll
        for (int i = 0; i < 8; i++) s += hist[c0i + i];
        unsigned int suf = s;
#pragma unroll
        for (int off = 1; off < 64; off <<= 1) {
            unsigned int tv = __shfl_down(suf, off);
            if (lane + off < 64) suf += tv;
        }
        unsigned int above = suf - s;
        if (suf >= kn2 && above < kn2) {
            unsigned int cum = above;
            for (int b = c0i + 7; ; b--) {
                unsigned int c2 = hist[b];
                if (cum + c2 >= kn2) { s_sel = (p23 << 9) | (unsigned int)b; s_kneed = kn2 - cum; s_eq = c2; break; }
                cum += c2;
            }
        }
    }
    __syncthreads();

    // ---- stable tie resolution (value==theta: lowest original indices win) ----
    const unsigned int theta = s_sel;
    const unsigned int kneedF = s_kneed, eqF = s_eq;
    const bool needOrder = (kneedF < eqF);
    int istar = NN;
    if (needOrder) {
        if (tid == 0) s_tiecnt = 0;
        __syncthreads();
#define TIE1(J, C, CI) if (v##J.C == theta) { \
            int pos = atomicAdd(&s_tiecnt, 1); \
            if (pos < 1024) s_tielist[pos] = (J) * 4096 + tid * 4 + (CI); }
#define TIE(J) TIE1(J, x, 0) TIE1(J, y, 1) TIE1(J, z, 2) TIE1(J, w, 3)
        CHUNKS(TIE)
#undef TIE
#undef TIE1
        __syncthreads();
        if (tid == 0) {
            int E = s_tiecnt; if (E > 1024) E = 1024;
            for (int aI = 1; aI < E; aI++) {
                int val = s_tielist[aI]; int bI = aI - 1;
                while (bI >= 0 && s_tielist[bI] > val) { s_tielist[bI + 1] = s_tielist[bI]; bI--; }
                s_tielist[bI + 1] = val;
            }
            int kk2 = (int)kneedF; if (kk2 > E) kk2 = E; if (kk2 < 1) kk2 = 1;
            s_tieidx = s_tielist[kk2 - 1];
        }
        __syncthreads();
        istar = s_tieidx;
    }

    // ---- write mask straight from registers ----
#define MV(u, idx) (((u) > theta) || ((u) == theta && (!needOrder || (idx) <= istar)) ? 1.0f : 0.0f)
#define WR(J) { \
        int e = (J) * 4096 + tid * 4; \
        float4 m; \
        m.x = MV(v##J.x, e + 0); \
        m.y = MV(v##J.y, e + 1); \
        m.z = MV(v##J.z, e + 2); \
        m.w = MV(v##J.w, e + 3); \
        *(float4*)(Or + e) = m; }
    CHUNKS(WR)
#undef WR
#undef MV
}

extern "C" void kernel_launch(void* const* d_in, const int* in_sizes, int n_in,
                              void* d_out, int out_size, void* d_ws, size_t ws_size,
                              hipStream_t stream) {
    // inputs: batch[B*N] i32 (unused), t[B] f32, U[B*N] f32, D[B*N] f32
    const float* T = (const float*)d_in[1];
    const float* U = (const float*)d_in[2];
    const float* D = (const float*)d_in[3];
    float* out = (float*)d_out;
    float* wout = out + (size_t)BB * NN;

    md_fused_kernel<<<BB, NT, 0, stream>>>(T, U, D, out, wout);
}